// Round 3
// baseline (42.707 us; speedup 1.0000x reference)
//
#include <hip/hip_runtime.h>

// SplatGaussian2D round 3: depth-4 software-pipelined uniform (scalar) param
// loads, no atomics (partial sums in d_ws + reduce kernel), no memset.
// w = exp2(log2(op) - q), q = (S0^2 log2e) rx^2 + (S1^2 log2e) ry^2,
// valid <=> q < 25 log2e. sin/cos(theta) via rx,ry * rsqrt — no atan2.

constexpr int   BN      = 8192;
constexpr int   NG      = 2048;
constexpr float SMIN    = 1.0f / 30.0f;
constexpr float SSPAN   = (1.0f / 0.75f - 1.0f / 30.0f);
constexpr float MUSCALE = 1.05f * 256.0f;
constexpr float LOG2E   = 1.44269504088896341f;
constexpr float QTHRESH = 25.0f * 1.44269504088896341f;
constexpr int   BLOCK   = 256;
constexpr int   GCHUNK  = 32;
constexpr int   NSPLIT  = NG / GCHUNK;                 // 64

__global__ __launch_bounds__(256) void splat_precompute(
    const float* __restrict__ xyz, const float* __restrict__ opac,
    const float* __restrict__ scal, const float* __restrict__ rot,
    float* __restrict__ gp)        // [N,8]
{
    const int g = blockIdx.x * 256 + threadIdx.x;
    if (g >= NG) return;
    const float mx = fminf(fmaxf(xyz[2 * g + 0], -1.0f), 1.0f) * MUSCALE;
    const float my = fminf(fmaxf(xyz[2 * g + 1], -1.0f), 1.0f) * MUSCALE;
    const float s0 = fminf(fmaxf(scal[2 * g + 0], 0.0f), 1.0f) * SSPAN + SMIN;
    const float s1 = fminf(fmaxf(scal[2 * g + 1], 0.0f), 1.0f) * SSPAN + SMIN;
    const float rr = rot[g];
    const float ang = (rr - floorf(rr)) * 6.283185307179586f;
    const float op  = fminf(fmaxf(opac[g], 0.0f), 1.0f);
    float4* o = reinterpret_cast<float4*>(gp + 8 * g);
    o[0] = make_float4(mx, my, cosf(ang), sinf(ang));
    o[1] = make_float4(s0 * s0 * LOG2E, s1 * s1 * LOG2E,
                       log2f(fmaxf(op, 1e-30f)), 0.0f);
}

__global__ __launch_bounds__(BLOCK) void splat_main(
    const float* __restrict__ xb,   // [B,2]
    const float* __restrict__ feat, // [N,9,3]
    const float* __restrict__ gp,   // [N,8]
    float* __restrict__ part)       // [NSPLIT,B,3]
{
    const int tid = threadIdx.x;
    const int r   = blockIdx.x * BLOCK + tid;
    const float ax = xb[2 * r + 0] - 256.0f;
    const float ay = xb[2 * r + 1] - 256.0f;
    const int g0 = blockIdx.y * GCHUNK;

    float o0 = 0.0f, o1 = 0.0f, o2 = 0.0f;

    const float4* __restrict__ gpv = reinterpret_cast<const float4*>(gp + 8 * g0);

    auto iter = [&](const float4& pa, const float4& pb, int g) {
        const float vx = ax - pa.x;
        const float vy = ay - pa.y;
        const float rx = fmaf(pa.z, vx, -pa.w * vy);
        const float ry = fmaf(pa.w, vx,  pa.z * vy);
        const float q  = fmaf(pb.x, rx * rx, pb.y * (ry * ry));
        const bool valid = q < QTHRESH;
        if (__any(valid)) {
            const float w  = valid ? exp2f(pb.z - q) : 0.0f;
            const float iv = rsqrtf(fmaxf(vx * vx + vy * vy, 1e-24f));
            const float s1v = rx * iv;
            const float c1v = ry * iv;
            const float s2v = 2.0f * s1v * c1v;
            const float c2v = fmaf(-2.0f * s1v, s1v, 1.0f);
            const float s3v = fmaf(s1v, c2v, c1v * s2v);
            const float c3v = fmaf(c1v, c2v, -s1v * s2v);
            const float s4v = 2.0f * s2v * c2v;
            const float c4v = fmaf(-2.0f * s2v, s2v, 1.0f);
            const float* __restrict__ fg = feat + g * 27;
            #pragma unroll
            for (int c = 0; c < 3; ++c) {
                float xc = fg[c];
                xc = fmaf(s1v, fg[3 + c],  xc);
                xc = fmaf(c1v, fg[6 + c],  xc);
                xc = fmaf(s2v, fg[9 + c],  xc);
                xc = fmaf(c2v, fg[12 + c], xc);
                xc = fmaf(s3v, fg[15 + c], xc);
                xc = fmaf(c3v, fg[18 + c], xc);
                xc = fmaf(s4v, fg[21 + c], xc);
                xc = fmaf(c4v, fg[24 + c], xc);
                const float e  = exp2f(-xc * LOG2E);
                const float wv = __fdividef(w, 1.0f + e);
                if (c == 0) o0 += wv; else if (c == 1) o1 += wv; else o2 += wv;
            }
        }
    };

    // depth-4 software pipeline over gaussians (params are wave-uniform)
    float4 c0 = gpv[0], c1 = gpv[1], c2 = gpv[2], c3 = gpv[3],
           c4 = gpv[4], c5 = gpv[5], c6 = gpv[6], c7 = gpv[7];
    for (int gi = 0; gi < GCHUNK; gi += 4) {
        float4 n0, n1, n2, n3, n4, n5, n6, n7;
        if (gi + 4 < GCHUNK) {
            const float4* nx = gpv + 2 * (gi + 4);
            n0 = nx[0]; n1 = nx[1]; n2 = nx[2]; n3 = nx[3];
            n4 = nx[4]; n5 = nx[5]; n6 = nx[6]; n7 = nx[7];
        }
        iter(c0, c1, g0 + gi + 0);
        iter(c2, c3, g0 + gi + 1);
        iter(c4, c5, g0 + gi + 2);
        iter(c6, c7, g0 + gi + 3);
        c0 = n0; c1 = n1; c2 = n2; c3 = n3;
        c4 = n4; c5 = n5; c6 = n6; c7 = n7;
    }

    float* p = part + ((size_t)blockIdx.y * BN + r) * 3;
    p[0] = o0; p[1] = o1; p[2] = o2;
}

__global__ __launch_bounds__(256) void splat_reduce(
    const float* __restrict__ part,   // [NSPLIT,B,3]
    float* __restrict__ out)          // [B,3]
{
    const int i = blockIdx.x * 256 + threadIdx.x;   // over B*3
    float s = 0.0f;
    #pragma unroll
    for (int k = 0; k < NSPLIT; ++k)
        s += part[(size_t)k * (BN * 3) + i];
    out[i] = s;
}

extern "C" void kernel_launch(void* const* d_in, const int* in_sizes, int n_in,
                              void* d_out, int out_size, void* d_ws, size_t ws_size,
                              hipStream_t stream) {
    const float* xb   = (const float*)d_in[0];
    const float* xyz  = (const float*)d_in[1];
    const float* feat = (const float*)d_in[2];
    const float* opac = (const float*)d_in[3];
    const float* scal = (const float*)d_in[4];
    const float* rot  = (const float*)d_in[5];
    float* out  = (float*)d_out;
    float* gp   = (float*)d_ws;                 // NG*8 floats = 64 KB
    float* part = gp + NG * 8;                  // NSPLIT*B*3 floats ≈ 6.3 MB

    splat_precompute<<<dim3((NG + 255) / 256), dim3(256), 0, stream>>>(xyz, opac, scal, rot, gp);
    splat_main<<<dim3(BN / BLOCK, NSPLIT), dim3(BLOCK), 0, stream>>>(xb, feat, gp, part);
    splat_reduce<<<dim3(BN * 3 / 256), dim3(256), 0, stream>>>(part, out);
}

// Round 4
// 28.269 us; speedup vs baseline: 1.5107x; 1.5107x over previous
//
#include <hip/hip_runtime.h>

// SplatGaussian2D round 4: fused single kernel, 8 blocks/CU (8 waves/SIMD),
// two-phase (light-test mask -> heavy SH only on set bits). Params + features
// staged in LDS, broadcast reads. w = exp2(log2(op) - q), q in log2e units.

constexpr int   BN      = 8192;
constexpr int   NG      = 2048;
constexpr float SMIN    = 1.0f / 30.0f;
constexpr float SSPAN   = (1.0f / 0.75f - 1.0f / 30.0f);
constexpr float MUSCALE = 1.05f * 256.0f;
constexpr float LOG2E   = 1.44269504088896341f;
constexpr float QT      = 25.0f * 1.44269504088896341f;   // valid <=> q < QT
constexpr int   BLOCK   = 256;
constexpr int   GCHUNK  = 32;
constexpr int   NSPLIT  = NG / GCHUNK;                    // 64

__global__ __launch_bounds__(BLOCK, 6) void splat_fused(
    const float* __restrict__ xb,   // [B,2]
    const float* __restrict__ xyz,  // [N,2]
    const float* __restrict__ feat, // [N,9,3]
    const float* __restrict__ opac, // [N]
    const float* __restrict__ scal, // [N,2]
    const float* __restrict__ rot,  // [N]
    float* __restrict__ out)        // [B,3]
{
    __shared__ float sp[GCHUNK * 8];    // mx,my,cs,sn | qsx,qsy,log2(op),pad
    __shared__ float sf[GCHUNK * 28];   // features, stride padded 27->28

    const int tid = threadIdx.x;
    const int g0  = blockIdx.y * GCHUNK;

    const int   r  = blockIdx.x * BLOCK + tid;
    const float ax = xb[2 * r + 0] - 256.0f;
    const float ay = xb[2 * r + 1] - 256.0f;

    if (tid < GCHUNK) {
        const int g = g0 + tid;
        const float mx = fminf(fmaxf(xyz[2 * g + 0], -1.0f), 1.0f) * MUSCALE;
        const float my = fminf(fmaxf(xyz[2 * g + 1], -1.0f), 1.0f) * MUSCALE;
        const float s0 = fminf(fmaxf(scal[2 * g + 0], 0.0f), 1.0f) * SSPAN + SMIN;
        const float s1 = fminf(fmaxf(scal[2 * g + 1], 0.0f), 1.0f) * SSPAN + SMIN;
        const float rr = rot[g];
        const float ang = (rr - floorf(rr)) * 6.283185307179586f;
        const float op  = fminf(fmaxf(opac[g], 0.0f), 1.0f);
        float* p = sp + tid * 8;
        p[0] = mx; p[1] = my; p[2] = __cosf(ang); p[3] = __sinf(ang);
        p[4] = s0 * s0 * LOG2E; p[5] = s1 * s1 * LOG2E;
        p[6] = log2f(fmaxf(op, 1e-30f)); p[7] = 0.0f;
    }
    for (int i = tid; i < GCHUNK * 27; i += BLOCK)
        sf[(i / 27) * 28 + (i % 27)] = feat[g0 * 27 + i];
    __syncthreads();

    const float4* __restrict__ sp4 = reinterpret_cast<const float4*>(sp);
    const float4* __restrict__ sf4 = reinterpret_cast<const float4*>(sf);

    // ---- phase A: light distance test, build wave-uniform mask ----
    unsigned mask = 0;
    #pragma unroll 4
    for (int gi = 0; gi < GCHUNK; ++gi) {
        const float4 a = sp4[2 * gi];
        const float4 b = sp4[2 * gi + 1];
        const float vx = ax - a.x;
        const float vy = ay - a.y;
        const float rx = fmaf(a.z, vx, -a.w * vy);
        const float ry = fmaf(a.w, vx,  a.z * vy);
        const float q  = fmaf(b.x, rx * rx, b.y * (ry * ry));
        if (__any(q < QT)) mask |= (1u << gi);
    }

    // ---- phase B: heavy SH/sigmoid path on set bits only ----
    float o0 = 0.0f, o1 = 0.0f, o2 = 0.0f;
    while (mask) {
        const int gi = __builtin_ctz(mask);
        mask &= (mask - 1);
        const float4 a = sp4[2 * gi];
        const float4 b = sp4[2 * gi + 1];
        const float vx = ax - a.x;
        const float vy = ay - a.y;
        const float rx = fmaf(a.z, vx, -a.w * vy);
        const float ry = fmaf(a.w, vx,  a.z * vy);
        const float q  = fmaf(b.x, rx * rx, b.y * (ry * ry));
        const float w  = (q < QT) ? exp2f(b.z - q) : 0.0f;

        const float iv  = rsqrtf(fmaxf(vx * vx + vy * vy, 1e-24f));
        const float s1v = rx * iv;
        const float c1v = ry * iv;
        const float s2v = 2.0f * s1v * c1v;
        const float c2v = fmaf(-2.0f * s1v, s1v, 1.0f);
        const float s3v = fmaf(s1v, c2v, c1v * s2v);
        const float c3v = fmaf(c1v, c2v, -s1v * s2v);
        const float s4v = 2.0f * s2v * c2v;
        const float c4v = fmaf(-2.0f * s2v, s2v, 1.0f);

        const float4 f0 = sf4[gi * 7 + 0];
        const float4 f1 = sf4[gi * 7 + 1];
        const float4 f2 = sf4[gi * 7 + 2];
        const float4 f3 = sf4[gi * 7 + 3];
        const float4 f4 = sf4[gi * 7 + 4];
        const float4 f5 = sf4[gi * 7 + 5];
        const float4 f6 = sf4[gi * 7 + 6];
        // layout: [1,s1,s1,s1, c1,c1,c1,s2, s2,s2,c2,c2, c2,s3,s3,s3,
        //          c3,c3,c3,s4, s4,s4,c4,c4, c4,-,-,-] per channel offset
        {
            float x0 = f0.x;                       // c=0 const
            x0 = fmaf(s1v, f0.w, x0);
            x0 = fmaf(c1v, f1.z, x0);
            x0 = fmaf(s2v, f2.y, x0);
            x0 = fmaf(c2v, f3.x, x0);
            x0 = fmaf(s3v, f3.w, x0);
            x0 = fmaf(c3v, f4.z, x0);
            x0 = fmaf(s4v, f5.y, x0);
            x0 = fmaf(c4v, f6.x, x0);
            float x1 = f0.y;                       // c=1
            x1 = fmaf(s1v, f1.x, x1);
            x1 = fmaf(c1v, f1.w, x1);
            x1 = fmaf(s2v, f2.z, x1);
            x1 = fmaf(c2v, f3.y, x1);
            x1 = fmaf(s3v, f4.x, x1);
            x1 = fmaf(c3v, f4.w, x1);
            x1 = fmaf(s4v, f5.z, x1);
            x1 = fmaf(c4v, f6.y, x1);
            float x2 = f0.z;                       // c=2
            x2 = fmaf(s1v, f1.y, x2);
            x2 = fmaf(c1v, f2.x, x2);
            x2 = fmaf(s2v, f2.w, x2);
            x2 = fmaf(c2v, f3.z, x2);
            x2 = fmaf(s3v, f4.y, x2);
            x2 = fmaf(c3v, f5.x, x2);
            x2 = fmaf(s4v, f5.w, x2);
            x2 = fmaf(c4v, f6.z, x2);
            o0 += __fdividef(w, 1.0f + exp2f(-x0 * LOG2E));
            o1 += __fdividef(w, 1.0f + exp2f(-x1 * LOG2E));
            o2 += __fdividef(w, 1.0f + exp2f(-x2 * LOG2E));
        }
    }

    atomicAdd(&out[3 * r + 0], o0);
    atomicAdd(&out[3 * r + 1], o1);
    atomicAdd(&out[3 * r + 2], o2);
}

extern "C" void kernel_launch(void* const* d_in, const int* in_sizes, int n_in,
                              void* d_out, int out_size, void* d_ws, size_t ws_size,
                              hipStream_t stream) {
    const float* xb   = (const float*)d_in[0];
    const float* xyz  = (const float*)d_in[1];
    const float* feat = (const float*)d_in[2];
    const float* opac = (const float*)d_in[3];
    const float* scal = (const float*)d_in[4];
    const float* rot  = (const float*)d_in[5];
    float* out = (float*)d_out;

    hipMemsetAsync(out, 0, (size_t)out_size * sizeof(float), stream);
    splat_fused<<<dim3(BN / BLOCK, NSPLIT), dim3(BLOCK), 0, stream>>>(
        xb, xyz, feat, opac, scal, rot, out);
}

// Round 5
// 27.298 us; speedup vs baseline: 1.5645x; 1.0356x over previous
//
#include <hip/hip_runtime.h>

// SplatGaussian2D round 5: gaussian-major. Each thread owns one gaussian
// (params + 27 features in REGISTERS, loaded once per block), inner loop
// streams rays via one broadcast ds_read_b64. Valid pairs (~0.2%) do heavy
// SH math + LDS atomicAdd into per-block acc; partials over 8 g-chunks.

constexpr int   BN    = 8192;
constexpr int   NG    = 2048;
constexpr float SMIN  = 1.0f / 30.0f;
constexpr float SSPAN = (1.0f / 0.75f - 1.0f / 30.0f);
constexpr float MUSCALE = 1.05f * 256.0f;
constexpr float LOG2E = 1.44269504088896341f;
constexpr float QT    = 25.0f * 1.44269504088896341f;
constexpr int   BLOCK = 256;
constexpr int   RC    = 32;              // rays per block
constexpr int   NRC   = BN / RC;         // 256 ray chunks
constexpr int   NGC   = NG / BLOCK;      // 8 gaussian chunks

// ws layout (floats): gp[NG*8] | featT[7*NG*4] | axy[BN*2] | part[NGC*BN*3]
constexpr int WS_GP   = 0;
constexpr int WS_FT   = WS_GP + NG * 8;
constexpr int WS_AXY  = WS_FT + 7 * NG * 4;
constexpr int WS_PART = WS_AXY + BN * 2;

__global__ __launch_bounds__(256) void splat_pre(
    const float* __restrict__ xb, const float* __restrict__ xyz,
    const float* __restrict__ feat, const float* __restrict__ opac,
    const float* __restrict__ scal, const float* __restrict__ rot,
    float* __restrict__ ws)
{
    const int i = blockIdx.x * 256 + threadIdx.x;   // grid covers BN
    // ray shift
    if (i < BN) {
        float2* axy = reinterpret_cast<float2*>(ws + WS_AXY);
        axy[i] = make_float2(xb[2 * i] - 256.0f, xb[2 * i + 1] - 256.0f);
    }
    if (i < NG) {
        const float mx = fminf(fmaxf(xyz[2 * i + 0], -1.0f), 1.0f) * MUSCALE;
        const float my = fminf(fmaxf(xyz[2 * i + 1], -1.0f), 1.0f) * MUSCALE;
        const float s0 = fminf(fmaxf(scal[2 * i + 0], 0.0f), 1.0f) * SSPAN + SMIN;
        const float s1 = fminf(fmaxf(scal[2 * i + 1], 0.0f), 1.0f) * SSPAN + SMIN;
        const float rr = rot[i];
        const float ang = (rr - floorf(rr)) * 6.283185307179586f;
        const float op  = fminf(fmaxf(opac[i], 0.0f), 1.0f);
        float4* gp4 = reinterpret_cast<float4*>(ws + WS_GP);
        gp4[2 * i + 0] = make_float4(mx, my, cosf(ang), sinf(ang));
        gp4[2 * i + 1] = make_float4(s0 * s0 * LOG2E, s1 * s1 * LOG2E,
                                     log2f(fmaxf(op, 1e-30f)), 0.0f);
        // feature transpose: featT4[k*NG + g] = feat[g, 4k..4k+3] (pad to 28)
        float4* ft = reinterpret_cast<float4*>(ws + WS_FT);
        const float* fg = feat + i * 27;
        #pragma unroll
        for (int k = 0; k < 7; ++k) {
            float a = fg[4 * k + 0];
            float b = (4 * k + 1 < 27) ? fg[4 * k + 1] : 0.0f;
            float c = (4 * k + 2 < 27) ? fg[4 * k + 2] : 0.0f;
            float d = (4 * k + 3 < 27) ? fg[4 * k + 3] : 0.0f;
            ft[k * NG + i] = make_float4(a, b, c, d);
        }
    }
}

__global__ __launch_bounds__(BLOCK) void splat_main(
    const float* __restrict__ ws_ro,
    float* __restrict__ part)            // [NGC, BN, 3]
{
    __shared__ float2 sray[RC];
    __shared__ float  sacc[RC * 3];

    const int tid = threadIdx.x;
    const int rc  = blockIdx.x;          // ray chunk
    const int gc  = blockIdx.y;          // gaussian chunk
    const int g   = gc * BLOCK + tid;

    // own-gaussian params -> registers (coalesced)
    const float4* gp4 = reinterpret_cast<const float4*>(ws_ro + WS_GP);
    const float4 pa = gp4[2 * g + 0];
    const float4 pb = gp4[2 * g + 1];
    const float mx = pa.x, my = pa.y, cs = pa.z, sn = pa.w;
    const float qsx = pb.x, qsy = pb.y, l2op = pb.z;
    const float nsn = -sn;

    // own-gaussian features -> registers (coalesced, reused over RC rays)
    const float4* ft = reinterpret_cast<const float4*>(ws_ro + WS_FT);
    const float4 f0 = ft[0 * NG + g];
    const float4 f1 = ft[1 * NG + g];
    const float4 f2 = ft[2 * NG + g];
    const float4 f3 = ft[3 * NG + g];
    const float4 f4 = ft[4 * NG + g];
    const float4 f5 = ft[5 * NG + g];
    const float4 f6 = ft[6 * NG + g];

    // stage rays + zero acc
    const float2* axy = reinterpret_cast<const float2*>(ws_ro + WS_AXY);
    if (tid < RC) sray[tid] = axy[rc * RC + tid];
    if (tid < RC * 3) sacc[tid] = 0.0f;
    __syncthreads();

    #pragma unroll 2
    for (int i = 0; i < RC; ++i) {
        const float2 rr = sray[i];                 // broadcast b64
        const float vx = rr.x - mx;
        const float vy = rr.y - my;
        const float rx = fmaf(cs, vx, nsn * vy);
        const float ry = fmaf(sn, vx, cs * vy);
        const float q  = fmaf(qsx, rx * rx, qsy * (ry * ry));
        if (q < QT) {
            const float w  = exp2f(l2op - q);
            const float iv = rsqrtf(fmaxf(vx * vx + vy * vy, 1e-24f));
            const float s1v = rx * iv;
            const float c1v = ry * iv;
            const float s2v = 2.0f * s1v * c1v;
            const float c2v = fmaf(-2.0f * s1v, s1v, 1.0f);
            const float s3v = fmaf(s1v, c2v, c1v * s2v);
            const float c3v = fmaf(c1v, c2v, -s1v * s2v);
            const float s4v = 2.0f * s2v * c2v;
            const float c4v = fmaf(-2.0f * s2v, s2v, 1.0f);

            float x0 = f0.x;
            x0 = fmaf(s1v, f0.w, x0);
            x0 = fmaf(c1v, f1.z, x0);
            x0 = fmaf(s2v, f2.y, x0);
            x0 = fmaf(c2v, f3.x, x0);
            x0 = fmaf(s3v, f3.w, x0);
            x0 = fmaf(c3v, f4.z, x0);
            x0 = fmaf(s4v, f5.y, x0);
            x0 = fmaf(c4v, f6.x, x0);
            float x1 = f0.y;
            x1 = fmaf(s1v, f1.x, x1);
            x1 = fmaf(c1v, f1.w, x1);
            x1 = fmaf(s2v, f2.z, x1);
            x1 = fmaf(c2v, f3.y, x1);
            x1 = fmaf(s3v, f4.x, x1);
            x1 = fmaf(c3v, f4.w, x1);
            x1 = fmaf(s4v, f5.z, x1);
            x1 = fmaf(c4v, f6.y, x1);
            float x2 = f0.z;
            x2 = fmaf(s1v, f1.y, x2);
            x2 = fmaf(c1v, f2.x, x2);
            x2 = fmaf(s2v, f2.w, x2);
            x2 = fmaf(c2v, f3.z, x2);
            x2 = fmaf(s3v, f4.y, x2);
            x2 = fmaf(c3v, f5.x, x2);
            x2 = fmaf(s4v, f5.w, x2);
            x2 = fmaf(c4v, f6.z, x2);

            atomicAdd(&sacc[3 * i + 0], __fdividef(w, 1.0f + exp2f(-x0 * LOG2E)));
            atomicAdd(&sacc[3 * i + 1], __fdividef(w, 1.0f + exp2f(-x1 * LOG2E)));
            atomicAdd(&sacc[3 * i + 2], __fdividef(w, 1.0f + exp2f(-x2 * LOG2E)));
        }
    }
    __syncthreads();

    if (tid < RC * 3)
        part[(size_t)gc * (BN * 3) + (size_t)rc * (RC * 3) + tid] = sacc[tid];
}

__global__ __launch_bounds__(256) void splat_reduce(
    const float* __restrict__ part, float* __restrict__ out)
{
    const int j = blockIdx.x * 256 + threadIdx.x;   // [0, BN*3)
    float s = 0.0f;
    #pragma unroll
    for (int k = 0; k < NGC; ++k)
        s += part[(size_t)k * (BN * 3) + j];
    out[j] = s;
}

extern "C" void kernel_launch(void* const* d_in, const int* in_sizes, int n_in,
                              void* d_out, int out_size, void* d_ws, size_t ws_size,
                              hipStream_t stream) {
    const float* xb   = (const float*)d_in[0];
    const float* xyz  = (const float*)d_in[1];
    const float* feat = (const float*)d_in[2];
    const float* opac = (const float*)d_in[3];
    const float* scal = (const float*)d_in[4];
    const float* rot  = (const float*)d_in[5];
    float* out = (float*)d_out;
    float* ws  = (float*)d_ws;
    float* part = ws + WS_PART;

    splat_pre<<<dim3(BN / 256), dim3(256), 0, stream>>>(xb, xyz, feat, opac, scal, rot, ws);
    splat_main<<<dim3(NRC, NGC), dim3(BLOCK), 0, stream>>>(ws, part);
    splat_reduce<<<dim3(BN * 3 / 256), dim3(256), 0, stream>>>(part, out);
}

// Round 6
// 24.801 us; speedup vs baseline: 1.7219x; 1.1006x over previous
//
#include <hip/hip_runtime.h>

// SplatGaussian2D round 6: leanest 2-dispatch pipeline. Gaussian-major main
// kernel (thread = one gaussian; params+features in registers, computed from
// raw inputs in-kernel), rays broadcast from LDS, rare heavy path, partial
// sums in d_ws, tiny reduce. No precompute kernel, no memset, no global atomics.

constexpr int   BN    = 8192;
constexpr int   NG    = 2048;
constexpr float SMIN  = 1.0f / 30.0f;
constexpr float SSPAN = (1.0f / 0.75f - 1.0f / 30.0f);
constexpr float MUSCALE = 1.05f * 256.0f;
constexpr float LOG2E = 1.44269504088896341f;
constexpr float QT    = 25.0f * 1.44269504088896341f;
constexpr int   BLOCK = 256;
constexpr int   RC    = 64;              // rays per block
constexpr int   NRC   = BN / RC;         // 128
constexpr int   NGC   = NG / BLOCK;      // 8

__global__ __launch_bounds__(BLOCK) void splat_main(
    const float* __restrict__ xb,   // [B,2]
    const float* __restrict__ xyz,  // [N,2]
    const float* __restrict__ feat, // [N,9,3]
    const float* __restrict__ opac, // [N]
    const float* __restrict__ scal, // [N,2]
    const float* __restrict__ rot,  // [N]
    float* __restrict__ part)       // [NGC, BN, 3]
{
    __shared__ float2 sray[RC];
    __shared__ float  sacc[RC * 3];

    const int tid = threadIdx.x;
    const int rc  = blockIdx.x;
    const int gc  = blockIdx.y;
    const int g   = gc * BLOCK + tid;

    // ---- own-gaussian params from raw inputs (once per block) ----
    const float2 xy = reinterpret_cast<const float2*>(xyz)[g];
    const float2 sc = reinterpret_cast<const float2*>(scal)[g];
    const float  rr = rot[g];
    const float  op = fminf(fmaxf(opac[g], 0.0f), 1.0f);
    const float mx = fminf(fmaxf(xy.x, -1.0f), 1.0f) * MUSCALE;
    const float my = fminf(fmaxf(xy.y, -1.0f), 1.0f) * MUSCALE;
    const float s0 = fminf(fmaxf(sc.x, 0.0f), 1.0f) * SSPAN + SMIN;
    const float s1 = fminf(fmaxf(sc.y, 0.0f), 1.0f) * SSPAN + SMIN;
    const float ang = (rr - floorf(rr)) * 6.283185307179586f;
    const float cs = __cosf(ang);
    const float sn = __sinf(ang);
    const float nsn = -sn;
    const float qsx = s0 * s0 * LOG2E;
    const float qsy = s1 * s1 * LOG2E;
    const float l2op = log2f(fmaxf(op, 1e-30f));

    // ---- own-gaussian features -> registers ----
    float f[27];
    {
        const float* __restrict__ fg = feat + g * 27;
        #pragma unroll
        for (int k = 0; k < 27; ++k) f[k] = fg[k];
    }

    // ---- stage rays, zero acc ----
    if (tid < RC) {
        const float2 t = reinterpret_cast<const float2*>(xb)[rc * RC + tid];
        sray[tid] = make_float2(t.x - 256.0f, t.y - 256.0f);
    }
    if (tid < RC * 3) sacc[tid] = 0.0f;
    __syncthreads();

    #pragma unroll 4
    for (int i = 0; i < RC; ++i) {
        const float2 a = sray[i];                  // broadcast ds_read_b64
        const float vx = a.x - mx;
        const float vy = a.y - my;
        const float rx = fmaf(cs, vx, nsn * vy);
        const float ry = fmaf(sn, vx,  cs * vy);
        const float q  = fmaf(qsx, rx * rx, qsy * (ry * ry));
        if (q < QT) {
            const float w  = exp2f(l2op - q);
            const float iv = rsqrtf(fmaxf(vx * vx + vy * vy, 1e-24f));
            const float s1v = rx * iv;
            const float c1v = ry * iv;
            const float s2v = 2.0f * s1v * c1v;
            const float c2v = fmaf(-2.0f * s1v, s1v, 1.0f);
            const float s3v = fmaf(s1v, c2v, c1v * s2v);
            const float c3v = fmaf(c1v, c2v, -s1v * s2v);
            const float s4v = 2.0f * s2v * c2v;
            const float c4v = fmaf(-2.0f * s2v, s2v, 1.0f);

            float x0 = f[0], x1 = f[1], x2 = f[2];
            x0 = fmaf(s1v, f[3],  x0); x1 = fmaf(s1v, f[4],  x1); x2 = fmaf(s1v, f[5],  x2);
            x0 = fmaf(c1v, f[6],  x0); x1 = fmaf(c1v, f[7],  x1); x2 = fmaf(c1v, f[8],  x2);
            x0 = fmaf(s2v, f[9],  x0); x1 = fmaf(s2v, f[10], x1); x2 = fmaf(s2v, f[11], x2);
            x0 = fmaf(c2v, f[12], x0); x1 = fmaf(c2v, f[13], x1); x2 = fmaf(c2v, f[14], x2);
            x0 = fmaf(s3v, f[15], x0); x1 = fmaf(s3v, f[16], x1); x2 = fmaf(s3v, f[17], x2);
            x0 = fmaf(c3v, f[18], x0); x1 = fmaf(c3v, f[19], x1); x2 = fmaf(c3v, f[20], x2);
            x0 = fmaf(s4v, f[21], x0); x1 = fmaf(s4v, f[22], x1); x2 = fmaf(s4v, f[23], x2);
            x0 = fmaf(c4v, f[24], x0); x1 = fmaf(c4v, f[25], x1); x2 = fmaf(c4v, f[26], x2);

            atomicAdd(&sacc[3 * i + 0], __fdividef(w, 1.0f + exp2f(-x0 * LOG2E)));
            atomicAdd(&sacc[3 * i + 1], __fdividef(w, 1.0f + exp2f(-x1 * LOG2E)));
            atomicAdd(&sacc[3 * i + 2], __fdividef(w, 1.0f + exp2f(-x2 * LOG2E)));
        }
    }
    __syncthreads();

    if (tid < RC * 3)
        part[(size_t)gc * (BN * 3) + (size_t)rc * (RC * 3) + tid] = sacc[tid];
}

__global__ __launch_bounds__(256) void splat_reduce(
    const float* __restrict__ part, float* __restrict__ out)
{
    const int j = blockIdx.x * 256 + threadIdx.x;   // [0, BN*3)
    float s = 0.0f;
    #pragma unroll
    for (int k = 0; k < NGC; ++k)
        s += part[(size_t)k * (BN * 3) + j];
    out[j] = s;
}

extern "C" void kernel_launch(void* const* d_in, const int* in_sizes, int n_in,
                              void* d_out, int out_size, void* d_ws, size_t ws_size,
                              hipStream_t stream) {
    const float* xb   = (const float*)d_in[0];
    const float* xyz  = (const float*)d_in[1];
    const float* feat = (const float*)d_in[2];
    const float* opac = (const float*)d_in[3];
    const float* scal = (const float*)d_in[4];
    const float* rot  = (const float*)d_in[5];
    float* out  = (float*)d_out;
    float* part = (float*)d_ws;                 // NGC*BN*3 floats ≈ 786 KB

    splat_main<<<dim3(NRC, NGC), dim3(BLOCK), 0, stream>>>(
        xb, xyz, feat, opac, scal, rot, part);
    splat_reduce<<<dim3(BN * 3 / 256), dim3(256), 0, stream>>>(part, out);
}

// Round 7
// 24.098 us; speedup vs baseline: 1.7722x; 1.0292x over previous
//
#include <hip/hip_runtime.h>

// SplatGaussian2D round 7: SINGLE dispatch. Block owns RC=8 rays vs ALL 2048
// gaussians (thread = 8 gaussians). Rays = wave-uniform scalar loads; params
// coalesced per chunk; features lazy-loaded only in the rare valid branch.
// Per-ray sums via sparse LDS atomics; block stores its 24 outputs directly.

constexpr int   BN    = 8192;
constexpr int   NG    = 2048;
constexpr float SMIN  = 1.0f / 30.0f;
constexpr float SSPAN = (1.0f / 0.75f - 1.0f / 30.0f);
constexpr float MUSCALE = 1.05f * 256.0f;
constexpr float LOG2E = 1.44269504088896341f;
constexpr float QT    = 25.0f * 1.44269504088896341f;
constexpr int   BLOCK = 256;
constexpr int   RC    = 8;               // rays per block
constexpr int   NBLK  = BN / RC;         // 1024 blocks
constexpr int   GPT   = NG / BLOCK;      // 8 gaussians per thread

__global__ __launch_bounds__(BLOCK, 4) void splat_one(
    const float* __restrict__ xb,   // [B,2]
    const float* __restrict__ xyz,  // [N,2]
    const float* __restrict__ feat, // [N,9,3]
    const float* __restrict__ opac, // [N]
    const float* __restrict__ scal, // [N,2]
    const float* __restrict__ rot,  // [N]
    float* __restrict__ out)        // [B,3]
{
    __shared__ float sacc[RC * 3];

    const int tid = threadIdx.x;
    const int rc  = blockIdx.x;

    // ---- rays: wave-uniform scalar loads ----
    const float* __restrict__ rb = xb + rc * (RC * 2);
    float rxs[RC], rys[RC];
    #pragma unroll
    for (int i = 0; i < RC; ++i) {
        rxs[i] = rb[2 * i + 0] - 256.0f;
        rys[i] = rb[2 * i + 1] - 256.0f;
    }

    if (tid < RC * 3) sacc[tid] = 0.0f;
    __syncthreads();

    #pragma unroll 1
    for (int k = 0; k < GPT; ++k) {
        const int g = k * BLOCK + tid;
        // own-gaussian params (coalesced)
        const float2 xy = reinterpret_cast<const float2*>(xyz)[g];
        const float2 sc = reinterpret_cast<const float2*>(scal)[g];
        const float  rr = rot[g];
        const float  op = fminf(fmaxf(opac[g], 0.0f), 1.0f);
        const float mx = fminf(fmaxf(xy.x, -1.0f), 1.0f) * MUSCALE;
        const float my = fminf(fmaxf(xy.y, -1.0f), 1.0f) * MUSCALE;
        const float s0 = fminf(fmaxf(sc.x, 0.0f), 1.0f) * SSPAN + SMIN;
        const float s1 = fminf(fmaxf(sc.y, 0.0f), 1.0f) * SSPAN + SMIN;
        const float ang = (rr - floorf(rr)) * 6.283185307179586f;
        const float cs = __cosf(ang);
        const float sn = __sinf(ang);
        const float nsn = -sn;
        const float qsx = s0 * s0 * LOG2E;
        const float qsy = s1 * s1 * LOG2E;
        const float l2op = log2f(fmaxf(op, 1e-30f));
        const float* __restrict__ fg = feat + (size_t)g * 27;

        #pragma unroll
        for (int i = 0; i < RC; ++i) {
            const float vx = rxs[i] - mx;
            const float vy = rys[i] - my;
            const float rx = fmaf(cs, vx, nsn * vy);
            const float ry = fmaf(sn, vx,  cs * vy);
            const float q  = fmaf(qsx, rx * rx, qsy * (ry * ry));
            if (q < QT) {
                const float w  = exp2f(l2op - q);
                const float iv = rsqrtf(fmaxf(vx * vx + vy * vy, 1e-24f));
                const float s1v = rx * iv;
                const float c1v = ry * iv;
                const float s2v = 2.0f * s1v * c1v;
                const float c2v = fmaf(-2.0f * s1v, s1v, 1.0f);
                const float s3v = fmaf(s1v, c2v, c1v * s2v);
                const float c3v = fmaf(c1v, c2v, -s1v * s2v);
                const float s4v = 2.0f * s2v * c2v;
                const float c4v = fmaf(-2.0f * s2v, s2v, 1.0f);

                // lazy feature load (rare path; L1/L2-cached on repeats)
                float f[27];
                #pragma unroll
                for (int t = 0; t < 27; ++t) f[t] = fg[t];

                float x0 = f[0], x1 = f[1], x2 = f[2];
                x0 = fmaf(s1v, f[3],  x0); x1 = fmaf(s1v, f[4],  x1); x2 = fmaf(s1v, f[5],  x2);
                x0 = fmaf(c1v, f[6],  x0); x1 = fmaf(c1v, f[7],  x1); x2 = fmaf(c1v, f[8],  x2);
                x0 = fmaf(s2v, f[9],  x0); x1 = fmaf(s2v, f[10], x1); x2 = fmaf(s2v, f[11], x2);
                x0 = fmaf(c2v, f[12], x0); x1 = fmaf(c2v, f[13], x1); x2 = fmaf(c2v, f[14], x2);
                x0 = fmaf(s3v, f[15], x0); x1 = fmaf(s3v, f[16], x1); x2 = fmaf(s3v, f[17], x2);
                x0 = fmaf(c3v, f[18], x0); x1 = fmaf(c3v, f[19], x1); x2 = fmaf(c3v, f[20], x2);
                x0 = fmaf(s4v, f[21], x0); x1 = fmaf(s4v, f[22], x1); x2 = fmaf(s4v, f[23], x2);
                x0 = fmaf(c4v, f[24], x0); x1 = fmaf(c4v, f[25], x1); x2 = fmaf(c4v, f[26], x2);

                atomicAdd(&sacc[3 * i + 0], __fdividef(w, 1.0f + exp2f(-x0 * LOG2E)));
                atomicAdd(&sacc[3 * i + 1], __fdividef(w, 1.0f + exp2f(-x1 * LOG2E)));
                atomicAdd(&sacc[3 * i + 2], __fdividef(w, 1.0f + exp2f(-x2 * LOG2E)));
            }
        }
    }
    __syncthreads();

    if (tid < RC * 3)
        out[rc * (RC * 3) + tid] = sacc[tid];
}

extern "C" void kernel_launch(void* const* d_in, const int* in_sizes, int n_in,
                              void* d_out, int out_size, void* d_ws, size_t ws_size,
                              hipStream_t stream) {
    const float* xb   = (const float*)d_in[0];
    const float* xyz  = (const float*)d_in[1];
    const float* feat = (const float*)d_in[2];
    const float* opac = (const float*)d_in[3];
    const float* scal = (const float*)d_in[4];
    const float* rot  = (const float*)d_in[5];
    float* out = (float*)d_out;

    splat_one<<<dim3(NBLK), dim3(BLOCK), 0, stream>>>(
        xb, xyz, feat, opac, scal, rot, out);
}

// Round 8
// 15.824 us; speedup vs baseline: 2.6988x; 1.5228x over previous
//
#include <hip/hip_runtime.h>

// SplatGaussian2D round 8: queue compaction. Light loop = pure quadratic-form
// test (q = A vx^2 + B vx vy + C vy^2, precomputed per gaussian, k-pipelined).
// Valid pairs -> LDS queue; processed 1 pair/lane afterwards (heavy math +
// feature gathers only for real pairs, ~0.23% density). Single dispatch.

constexpr int   BN    = 8192;
constexpr int   NG    = 2048;
constexpr float SMIN  = 1.0f / 30.0f;
constexpr float SSPAN = (1.0f / 0.75f - 1.0f / 30.0f);
constexpr float MUSCALE = 1.05f * 256.0f;
constexpr float LOG2E = 1.44269504088896341f;
constexpr float QT    = 25.0f * 1.44269504088896341f;
constexpr float TWOPI = 6.283185307179586f;
constexpr int   BLOCK = 256;
constexpr int   RC    = 4;               // rays per block
constexpr int   NBLK  = BN / RC;         // 2048 blocks
constexpr int   GPT   = NG / BLOCK;      // 8 k-steps
constexpr int   QMAX  = 2048;            // LDS queue entries (avg ~19/block)

__global__ __launch_bounds__(BLOCK) void splat_one(
    const float* __restrict__ xb,   // [B,2]
    const float* __restrict__ xyz,  // [N,2]
    const float* __restrict__ feat, // [N,9,3]
    const float* __restrict__ opac, // [N]
    const float* __restrict__ scal, // [N,2]
    const float* __restrict__ rot,  // [N]
    float* __restrict__ out)        // [B,3]
{
    __shared__ float    sray[RC * 2];
    __shared__ float    sacc[RC * 3];
    __shared__ unsigned queue[QMAX];
    __shared__ int      qcnt;

    const int tid = threadIdx.x;
    const int rc  = blockIdx.x;

    if (tid == 0) qcnt = 0;
    if (tid < RC) {
        const float2 t = reinterpret_cast<const float2*>(xb)[rc * RC + tid];
        sray[2 * tid + 0] = t.x - 256.0f;
        sray[2 * tid + 1] = t.y - 256.0f;
    }
    if (tid < RC * 3) sacc[tid] = 0.0f;
    __syncthreads();

    float rxs[RC], rys[RC];
    #pragma unroll
    for (int i = 0; i < RC; ++i) { rxs[i] = sray[2 * i]; rys[i] = sray[2 * i + 1]; }

    // ---- light phase: pipelined param loads, pure quadratic test ----
    float2 xy = reinterpret_cast<const float2*>(xyz)[tid];
    float2 sc = reinterpret_cast<const float2*>(scal)[tid];
    float  rr = rot[tid];

    for (int k = 0; k < GPT; ++k) {
        float2 nxy, nsc; float nrr;
        if (k + 1 < GPT) {
            const int gn = (k + 1) * BLOCK + tid;
            nxy = reinterpret_cast<const float2*>(xyz)[gn];
            nsc = reinterpret_cast<const float2*>(scal)[gn];
            nrr = rot[gn];
        }
        const float mx = fminf(fmaxf(xy.x, -1.0f), 1.0f) * MUSCALE;
        const float my = fminf(fmaxf(xy.y, -1.0f), 1.0f) * MUSCALE;
        const float s0 = fminf(fmaxf(sc.x, 0.0f), 1.0f) * SSPAN + SMIN;
        const float s1 = fminf(fmaxf(sc.y, 0.0f), 1.0f) * SSPAN + SMIN;
        const float ang = (rr - floorf(rr)) * TWOPI;
        float sn, cs;
        __sincosf(ang, &sn, &cs);
        const float qsx = s0 * s0 * LOG2E;
        const float qsy = s1 * s1 * LOG2E;
        const float c2 = cs * cs, s2 = sn * sn;
        const float A  = fmaf(qsx, c2, qsy * s2);
        const float C  = fmaf(qsx, s2, qsy * c2);
        const float Bq = 2.0f * cs * sn * (qsy - qsx);
        const unsigned gbase = (unsigned)(k * BLOCK + tid) << 2;

        #pragma unroll
        for (int i = 0; i < RC; ++i) {
            const float vx = rxs[i] - mx;
            const float vy = rys[i] - my;
            const float q  = fmaf(A, vx * vx, fmaf(Bq, vx * vy, C * (vy * vy)));
            if (q < QT) {
                const int idx = atomicAdd(&qcnt, 1);
                if (idx < QMAX) queue[idx] = gbase | (unsigned)i;
            }
        }
        xy = nxy; sc = nsc; rr = nrr;
    }
    __syncthreads();

    // ---- heavy phase: one valid pair per lane ----
    const int n = min(qcnt, QMAX);
    for (int j = tid; j < n; j += BLOCK) {
        const unsigned e = queue[j];
        const int g = (int)(e >> 2);
        const int i = (int)(e & 3u);

        const float2 gxy = reinterpret_cast<const float2*>(xyz)[g];
        const float2 gsc = reinterpret_cast<const float2*>(scal)[g];
        const float  grr = rot[g];
        const float  op  = fminf(fmaxf(opac[g], 0.0f), 1.0f);
        const float mx = fminf(fmaxf(gxy.x, -1.0f), 1.0f) * MUSCALE;
        const float my = fminf(fmaxf(gxy.y, -1.0f), 1.0f) * MUSCALE;
        const float s0 = fminf(fmaxf(gsc.x, 0.0f), 1.0f) * SSPAN + SMIN;
        const float s1 = fminf(fmaxf(gsc.y, 0.0f), 1.0f) * SSPAN + SMIN;
        const float ang = (grr - floorf(grr)) * TWOPI;
        float sn, cs;
        __sincosf(ang, &sn, &cs);

        const float vx = sray[2 * i + 0] - mx;
        const float vy = sray[2 * i + 1] - my;
        const float rx = fmaf(cs, vx, -sn * vy);
        const float ry = fmaf(sn, vx,  cs * vy);
        const float q  = fmaf(s0 * s0 * LOG2E, rx * rx,
                              (s1 * s1 * LOG2E) * (ry * ry));
        const float w  = exp2f(log2f(fmaxf(op, 1e-30f)) - q);

        const float iv  = rsqrtf(fmaxf(vx * vx + vy * vy, 1e-24f));
        const float s1v = rx * iv;
        const float c1v = ry * iv;
        const float s2v = 2.0f * s1v * c1v;
        const float c2v = fmaf(-2.0f * s1v, s1v, 1.0f);
        const float s3v = fmaf(s1v, c2v, c1v * s2v);
        const float c3v = fmaf(c1v, c2v, -s1v * s2v);
        const float s4v = 2.0f * s2v * c2v;
        const float c4v = fmaf(-2.0f * s2v, s2v, 1.0f);

        const float* __restrict__ fg = feat + (size_t)g * 27;
        float x0 = fg[0], x1 = fg[1], x2 = fg[2];
        x0 = fmaf(s1v, fg[3],  x0); x1 = fmaf(s1v, fg[4],  x1); x2 = fmaf(s1v, fg[5],  x2);
        x0 = fmaf(c1v, fg[6],  x0); x1 = fmaf(c1v, fg[7],  x1); x2 = fmaf(c1v, fg[8],  x2);
        x0 = fmaf(s2v, fg[9],  x0); x1 = fmaf(s2v, fg[10], x1); x2 = fmaf(s2v, fg[11], x2);
        x0 = fmaf(c2v, fg[12], x0); x1 = fmaf(c2v, fg[13], x1); x2 = fmaf(c2v, fg[14], x2);
        x0 = fmaf(s3v, fg[15], x0); x1 = fmaf(s3v, fg[16], x1); x2 = fmaf(s3v, fg[17], x2);
        x0 = fmaf(c3v, fg[18], x0); x1 = fmaf(c3v, fg[19], x1); x2 = fmaf(c3v, fg[20], x2);
        x0 = fmaf(s4v, fg[21], x0); x1 = fmaf(s4v, fg[22], x1); x2 = fmaf(s4v, fg[23], x2);
        x0 = fmaf(c4v, fg[24], x0); x1 = fmaf(c4v, fg[25], x1); x2 = fmaf(c4v, fg[26], x2);

        atomicAdd(&sacc[3 * i + 0], __fdividef(w, 1.0f + exp2f(-x0 * LOG2E)));
        atomicAdd(&sacc[3 * i + 1], __fdividef(w, 1.0f + exp2f(-x1 * LOG2E)));
        atomicAdd(&sacc[3 * i + 2], __fdividef(w, 1.0f + exp2f(-x2 * LOG2E)));
    }
    __syncthreads();

    if (tid < RC * 3)
        out[rc * (RC * 3) + tid] = sacc[tid];
}

extern "C" void kernel_launch(void* const* d_in, const int* in_sizes, int n_in,
                              void* d_out, int out_size, void* d_ws, size_t ws_size,
                              hipStream_t stream) {
    const float* xb   = (const float*)d_in[0];
    const float* xyz  = (const float*)d_in[1];
    const float* feat = (const float*)d_in[2];
    const float* opac = (const float*)d_in[3];
    const float* scal = (const float*)d_in[4];
    const float* rot  = (const float*)d_in[5];
    float* out = (float*)d_out;

    splat_one<<<dim3(NBLK), dim3(BLOCK), 0, stream>>>(
        xb, xyz, feat, opac, scal, rot, out);
}